// Round 1
// baseline (339.178 us; speedup 1.0000x reference)
//
#include <hip/hip_runtime.h>

#define B_ 4
#define S_ 2048
#define D_ 512
#define H_ 8
#define HD_ 64
#define M_TOT 8192  // B_*S_

typedef __attribute__((ext_vector_type(8))) short short8;
typedef __attribute__((ext_vector_type(4))) float f32x4;
typedef unsigned short u16;
typedef unsigned int u32;

__device__ __forceinline__ u16 f2bf(float f) {
  union { float f; u32 u; } v; v.f = f;
  u32 u = v.u;
  return (u16)((u + 0x7fffu + ((u >> 16) & 1u)) >> 16);  // RNE
}

// ---------------------------------------------------------------- cast to bf16
__global__ __launch_bounds__(256) void cast_kernel(
    const float* __restrict__ x, const float* __restrict__ wq, const float* __restrict__ wk,
    const float* __restrict__ wv, const float* __restrict__ wo,
    u16* __restrict__ xb, u16* __restrict__ wqb, u16* __restrict__ wkb,
    u16* __restrict__ wvb, u16* __restrict__ wob)
{
  const int NX = M_TOT * D_ / 4;  // 1048576 float4s
  const int NW = D_ * D_ / 4;     // 65536
  int i = blockIdx.x * 256 + threadIdx.x;
  const float* src; u16* dst; int o;
  if (i < NX)               { src = x;  dst = xb;  o = i; }
  else if (i < NX + NW)     { src = wq; dst = wqb; o = i - NX; }
  else if (i < NX + 2 * NW) { src = wk; dst = wkb; o = i - NX - NW; }
  else if (i < NX + 3 * NW) { src = wv; dst = wvb; o = i - NX - 2 * NW; }
  else if (i < NX + 4 * NW) { src = wo; dst = wob; o = i - NX - 3 * NW; }
  else return;
  f32x4 v = ((const f32x4*)src)[o];
  u32 p0 = (u32)f2bf(v[0]) | ((u32)f2bf(v[1]) << 16);
  u32 p1 = (u32)f2bf(v[2]) | ((u32)f2bf(v[3]) << 16);
  u32* d = (u32*)(dst + (long)o * 4);
  d[0] = p0; d[1] = p1;
}

// ---------------------------------------------------------------- bf16 GEMM, B^T layout
// C[m][n] = sum_k A[m][k]*Bw[n][k] + bias[n]
// mode 0: out_bf[((b*H+h)*S+s)*HD+hd] = bf16(C*scale)   (QKV projection layout)
// mode 1: out_f32[m*D+n] = C + resid[m*D+n]             (out-proj + residual)
#define BM 128
#define BN 128
#define BKK 64
#define LDT 88  // LDS row stride (u16): 64 + 24 pad -> 176B rows, 2-way banks on frag reads

__global__ __launch_bounds__(256) void gemm_bt(
    const u16* __restrict__ A, const u16* __restrict__ Bw,
    const float* __restrict__ bias, const float* __restrict__ resid,
    u16* __restrict__ out_bf, float* __restrict__ out_f32,
    float scale, int mode)
{
  __shared__ u16 As[BM][LDT];
  __shared__ u16 Bs[BN][LDT];
  const int K = D_;
  const int tid = threadIdx.x;
  const int lane = tid & 63;
  const int wave = tid >> 6;
  const int wr = wave >> 1, wc = wave & 1;  // 2x2 waves, 64x64 each
  const int m0 = blockIdx.x * BM, n0 = blockIdx.y * BN;
  const int l15 = lane & 15, l4 = lane >> 4;

  f32x4 acc[4][4];
#pragma unroll
  for (int i = 0; i < 4; ++i)
#pragma unroll
    for (int j = 0; j < 4; ++j)
      acc[i][j] = (f32x4){0.f, 0.f, 0.f, 0.f};

  const int srow = tid >> 1, shalf = tid & 1;  // each thread stages 32 u16 of one row
  const u16* aSrc = A + (long)(m0 + srow) * K + shalf * 32;
  const u16* bSrc = Bw + (long)(n0 + srow) * K + shalf * 32;
  u16* aDst = &As[srow][shalf * 32];
  u16* bDst = &Bs[srow][shalf * 32];

  for (int k0 = 0; k0 < K; k0 += BKK) {
    uint4 a4[4], b4[4];
    const uint4* ag = (const uint4*)(aSrc + k0);
    const uint4* bg = (const uint4*)(bSrc + k0);
#pragma unroll
    for (int q = 0; q < 4; ++q) { a4[q] = ag[q]; b4[q] = bg[q]; }
    __syncthreads();  // previous tile's frag reads done
#pragma unroll
    for (int q = 0; q < 4; ++q) {
      ((uint4*)aDst)[q] = a4[q];
      ((uint4*)bDst)[q] = b4[q];
    }
    __syncthreads();
#pragma unroll
    for (int kb = 0; kb < 2; ++kb) {
      short8 af[4], bf[4];
      const int ko = kb * 32 + l4 * 8;
#pragma unroll
      for (int i = 0; i < 4; ++i) {
        af[i] = *(const short8*)&As[wr * 64 + i * 16 + l15][ko];
        bf[i] = *(const short8*)&Bs[wc * 64 + i * 16 + l15][ko];
      }
#pragma unroll
      for (int i = 0; i < 4; ++i)
#pragma unroll
        for (int j = 0; j < 4; ++j)
          acc[i][j] = __builtin_amdgcn_mfma_f32_16x16x32_bf16(af[i], bf[j], acc[i][j], 0, 0, 0);
    }
  }

#pragma unroll
  for (int i = 0; i < 4; ++i) {
#pragma unroll
    for (int j = 0; j < 4; ++j) {
#pragma unroll
      for (int r = 0; r < 4; ++r) {
        int m = m0 + wr * 64 + i * 16 + l4 * 4 + r;
        int n = n0 + wc * 64 + j * 16 + l15;
        float v = acc[i][j][r] + bias[n];
        if (mode == 0) {
          v *= scale;
          int b = m >> 11, s = m & 2047;
          int h = n >> 6, hd = n & 63;
          out_bf[((long)(b * H_ + h) * S_ + s) * HD_ + hd] = f2bf(v);
        } else {
          long idx = (long)m * D_ + n;
          out_f32[idx] = v + resid[idx];
        }
      }
    }
  }
}

// ---------------------------------------------------------------- flash attention (bf16 MFMA)
// Q pre-scaled by 1/8. Per block: (b,h, 128 q-rows); 4 waves x 32 rows; TK=64.
__global__ __launch_bounds__(256) void attn_kernel(
    const u16* __restrict__ Qg, const u16* __restrict__ Kg,
    const u16* __restrict__ Vg, u16* __restrict__ ctx)
{
  __shared__ u16 KsBuf[64 * 64];
  __shared__ u16 VtBuf[64 * 64];   // V transposed: [d][j]
  __shared__ u16 PsBuf[128 * 64];
  char* KsB = (char*)KsBuf;
  char* VtB = (char*)VtBuf;
  char* PsB = (char*)PsBuf;

  const int tid = threadIdx.x, lane = tid & 63, wave = tid >> 6;
  const int l15 = lane & 15, l4 = lane >> 4;
  const int bh = blockIdx.y;
  const int q0 = blockIdx.x * 128;
  const int b = bh >> 3, h = bh & 7;
  const long hoff = (long)bh * S_ * HD_;
  const u16* Qh = Qg + hoff;
  const u16* Kh = Kg + hoff;
  const u16* Vh = Vg + hoff;
  const int wrow = wave * 32;

  // Q fragments straight from global (read once, held in regs)
  short8 qf[2][2];
#pragma unroll
  for (int mf = 0; mf < 2; ++mf)
#pragma unroll
    for (int kb = 0; kb < 2; ++kb) {
      int row = q0 + wrow + mf * 16 + l15;
      qf[mf][kb] = *(const short8*)&Qh[(long)row * HD_ + kb * 32 + l4 * 8];
    }

  float mst[2][4], lst[2][4];
  f32x4 oacc[2][4];
#pragma unroll
  for (int mf = 0; mf < 2; ++mf)
#pragma unroll
    for (int r = 0; r < 4; ++r) { mst[mf][r] = -1e30f; lst[mf][r] = 0.f; }
#pragma unroll
  for (int mf = 0; mf < 2; ++mf)
#pragma unroll
    for (int nf = 0; nf < 4; ++nf)
      oacc[mf][nf] = (f32x4){0.f, 0.f, 0.f, 0.f};

  const int kj = tid >> 2, kq = tid & 3;  // K staging: row kj, 16-elem chunk kq
  const int vj = tid & 63, vdg = tid >> 6;  // V staging: col j=vj, d-group vdg

  for (int kv0 = 0; kv0 < S_; kv0 += 64) {
    const uint4* ksrc = (const uint4*)&Kh[(long)(kv0 + kj) * HD_ + kq * 16];
    uint4 kv0a = ksrc[0], kv1a = ksrc[1];
    const uint4* vsrc = (const uint4*)&Vh[(long)(kv0 + vj) * HD_ + vdg * 16];
    uint4 vv0 = vsrc[0], vv1 = vsrc[1];
    __syncthreads();  // previous tile fully consumed
    {  // K tile, XOR-swizzled rows (128B rows)
      int base = kj * 128, sw = (kj & 7) << 4;
      *(uint4*)(KsB + base + ((kq * 32) ^ sw)) = kv0a;
      *(uint4*)(KsB + base + ((kq * 32 + 16) ^ sw)) = kv1a;
    }
    {  // V transpose into Vt[d][j], swizzled
      union { uint4 v; u16 u[8]; } a0, a1;
      a0.v = vv0; a1.v = vv1;
#pragma unroll
      for (int e = 0; e < 8; ++e) {
        int d0 = vdg * 16 + e;
        *(u16*)(VtB + d0 * 128 + ((vj * 2) ^ ((d0 & 7) << 4))) = a0.u[e];
        int d1 = d0 + 8;
        *(u16*)(VtB + d1 * 128 + ((vj * 2) ^ ((d1 & 7) << 4))) = a1.u[e];
      }
    }
    __syncthreads();

    // S = Q @ K^T  (Q pre-scaled)
    f32x4 sacc[2][4];
#pragma unroll
    for (int mf = 0; mf < 2; ++mf)
#pragma unroll
      for (int nf = 0; nf < 4; ++nf)
        sacc[mf][nf] = (f32x4){0.f, 0.f, 0.f, 0.f};
#pragma unroll
    for (int kb = 0; kb < 2; ++kb) {
      short8 kf[4];
#pragma unroll
      for (int nf = 0; nf < 4; ++nf) {
        int krow = nf * 16 + l15;
        kf[nf] = *(const short8*)(KsB + krow * 128 + ((kb * 64 + l4 * 16) ^ ((krow & 7) << 4)));
      }
#pragma unroll
      for (int mf = 0; mf < 2; ++mf)
#pragma unroll
        for (int nf = 0; nf < 4; ++nf)
          sacc[mf][nf] = __builtin_amdgcn_mfma_f32_16x16x32_bf16(qf[mf][kb], kf[nf], sacc[mf][nf], 0, 0, 0);
    }

    // online softmax (rows are wave-local; reduce across the 16 col-lanes)
#pragma unroll
    for (int mf = 0; mf < 2; ++mf) {
#pragma unroll
      for (int r = 0; r < 4; ++r) {
        float mx = fmaxf(fmaxf(sacc[mf][0][r], sacc[mf][1][r]),
                         fmaxf(sacc[mf][2][r], sacc[mf][3][r]));
        mx = fmaxf(mx, __shfl_xor(mx, 1));
        mx = fmaxf(mx, __shfl_xor(mx, 2));
        mx = fmaxf(mx, __shfl_xor(mx, 4));
        mx = fmaxf(mx, __shfl_xor(mx, 8));
        float mnew = fmaxf(mst[mf][r], mx);
        float rs = __expf(mst[mf][r] - mnew);
        mst[mf][r] = mnew;
        float rsum = 0.f;
#pragma unroll
        for (int nf = 0; nf < 4; ++nf) {
          float p = __expf(sacc[mf][nf][r] - mnew);
          sacc[mf][nf][r] = p;
          rsum += p;
        }
        rsum += __shfl_xor(rsum, 1);
        rsum += __shfl_xor(rsum, 2);
        rsum += __shfl_xor(rsum, 4);
        rsum += __shfl_xor(rsum, 8);
        lst[mf][r] = lst[mf][r] * rs + rsum;
#pragma unroll
        for (int nf = 0; nf < 4; ++nf)
          oacc[mf][nf][r] *= rs;
      }
    }
    // P -> bf16 -> LDS (swizzled); rows are wave-private so no barrier needed
#pragma unroll
    for (int mf = 0; mf < 2; ++mf)
#pragma unroll
      for (int nf = 0; nf < 4; ++nf)
#pragma unroll
        for (int r = 0; r < 4; ++r) {
          int prow = wrow + mf * 16 + l4 * 4 + r;
          int pcol = nf * 16 + l15;
          *(u16*)(PsB + prow * 128 + ((pcol * 2) ^ ((prow & 7) << 4))) = f2bf(sacc[mf][nf][r]);
        }
    asm volatile("s_waitcnt lgkmcnt(0)" ::: "memory");

    // O += P @ V
#pragma unroll
    for (int jb = 0; jb < 2; ++jb) {
      short8 pf[2], vf[4];
#pragma unroll
      for (int mf = 0; mf < 2; ++mf) {
        int prow = wrow + mf * 16 + l15;
        pf[mf] = *(const short8*)(PsB + prow * 128 + ((jb * 64 + l4 * 16) ^ ((prow & 7) << 4)));
      }
#pragma unroll
      for (int nf = 0; nf < 4; ++nf) {
        int vrow = nf * 16 + l15;
        vf[nf] = *(const short8*)(VtB + vrow * 128 + ((jb * 64 + l4 * 16) ^ ((vrow & 7) << 4)));
      }
#pragma unroll
      for (int mf = 0; mf < 2; ++mf)
#pragma unroll
        for (int nf = 0; nf < 4; ++nf)
          oacc[mf][nf] = __builtin_amdgcn_mfma_f32_16x16x32_bf16(pf[mf], vf[nf], oacc[mf][nf], 0, 0, 0);
    }
  }

  // epilogue: normalize and write context [B,S,D]
#pragma unroll
  for (int mf = 0; mf < 2; ++mf) {
#pragma unroll
    for (int r = 0; r < 4; ++r) {
      float inv = 1.f / lst[mf][r];
      int s = q0 + wrow + mf * 16 + l4 * 4 + r;
#pragma unroll
      for (int nf = 0; nf < 4; ++nf) {
        int d = nf * 16 + l15;
        ctx[((long)(b * S_ + s)) * D_ + h * HD_ + d] = f2bf(oacc[mf][nf][r] * inv);
      }
    }
  }
}

// ---------------------------------------------------------------- LayerNorm (wave per row)
__global__ __launch_bounds__(256) void ln_kernel(
    const float* __restrict__ y, const float* __restrict__ gamma,
    const float* __restrict__ beta, float* __restrict__ out)
{
  const int lane = threadIdx.x & 63, wave = threadIdx.x >> 6;
  const long row = (long)blockIdx.x * 4 + wave;
  const float* yr = y + row * D_;
  f32x4 v0 = *(const f32x4*)&yr[lane * 8];
  f32x4 v1 = *(const f32x4*)&yr[lane * 8 + 4];
  float s = 0.f, ss = 0.f;
#pragma unroll
  for (int e = 0; e < 4; ++e) {
    s += v0[e]; ss += v0[e] * v0[e];
    s += v1[e]; ss += v1[e] * v1[e];
  }
#pragma unroll
  for (int msk = 1; msk < 64; msk <<= 1) {
    s += __shfl_xor(s, msk);
    ss += __shfl_xor(ss, msk);
  }
  float mean = s * (1.f / 512.f);
  float var = ss * (1.f / 512.f) - mean * mean;
  float inv = rsqrtf(var + 1e-5f);
  f32x4 g0 = *(const f32x4*)&gamma[lane * 8];
  f32x4 g1 = *(const f32x4*)&gamma[lane * 8 + 4];
  f32x4 b0 = *(const f32x4*)&beta[lane * 8];
  f32x4 b1 = *(const f32x4*)&beta[lane * 8 + 4];
  f32x4 o0, o1;
#pragma unroll
  for (int e = 0; e < 4; ++e) {
    o0[e] = (v0[e] - mean) * inv * g0[e] + b0[e];
    o1[e] = (v1[e] - mean) * inv * g1[e] + b1[e];
  }
  *(f32x4*)&out[row * D_ + lane * 8] = o0;
  *(f32x4*)&out[row * D_ + lane * 8 + 4] = o1;
}

// ---------------------------------------------------------------- launch
extern "C" void kernel_launch(void* const* d_in, const int* in_sizes, int n_in,
                              void* d_out, int out_size, void* d_ws, size_t ws_size,
                              hipStream_t stream) {
  const float* x  = (const float*)d_in[0];
  const float* Wq = (const float*)d_in[1];
  const float* bq = (const float*)d_in[2];
  const float* Wk = (const float*)d_in[3];
  const float* bk = (const float*)d_in[4];
  const float* Wv = (const float*)d_in[5];
  const float* bv = (const float*)d_in[6];
  const float* Wo = (const float*)d_in[7];
  const float* bo = (const float*)d_in[8];
  const float* lg = (const float*)d_in[9];
  const float* lb = (const float*)d_in[10];

  char* ws = (char*)d_ws;
  const size_t SZ_XB = (size_t)M_TOT * D_ * 2;  // 8 MiB region per [M,D] bf16
  const size_t SZ_W  = (size_t)D_ * D_ * 2;
  u16* xb   = (u16*)(ws);
  u16* q_ws = (u16*)(ws + SZ_XB);
  u16* k_ws = (u16*)(ws + 2 * SZ_XB);
  u16* v_ws = (u16*)(ws + 3 * SZ_XB);
  u16* c_ws = (u16*)(ws + 4 * SZ_XB);
  u16* wqb  = (u16*)(ws + 5 * SZ_XB);
  u16* wkb  = (u16*)(ws + 5 * SZ_XB + SZ_W);
  u16* wvb  = (u16*)(ws + 5 * SZ_XB + 2 * SZ_W);
  u16* wob  = (u16*)(ws + 5 * SZ_XB + 3 * SZ_W);
  // y (fp32, 16 MiB) aliases xb+q_ws — both dead before out-proj writes it
  float* yf = (float*)(ws);

  cast_kernel<<<5120, 256, 0, stream>>>(x, Wq, Wk, Wv, Wo, xb, wqb, wkb, wvb, wob);

  dim3 gg(M_TOT / BM, D_ / BN);  // 64 x 4
  // Q projection pre-scaled by 1/sqrt(HD) = 1/8 (exact power of two)
  gemm_bt<<<gg, 256, 0, stream>>>(xb, wqb, bq, nullptr, q_ws, nullptr, 0.125f, 0);
  gemm_bt<<<gg, 256, 0, stream>>>(xb, wkb, bk, nullptr, k_ws, nullptr, 1.0f, 0);
  gemm_bt<<<gg, 256, 0, stream>>>(xb, wvb, bv, nullptr, v_ws, nullptr, 1.0f, 0);

  attn_kernel<<<dim3(S_ / 128, B_ * H_), 256, 0, stream>>>(q_ws, k_ws, v_ws, c_ws);

  gemm_bt<<<gg, 256, 0, stream>>>(c_ws, wob, bo, x, nullptr, yf, 1.0f, 1);

  ln_kernel<<<M_TOT / 4, 256, 0, stream>>>(yf, lg, lb, (float*)d_out);
}

// Round 2
// 321.303 us; speedup vs baseline: 1.0556x; 1.0556x over previous
//
#include <hip/hip_runtime.h>
#include <hip/hip_bf16.h>

#define B_ 4
#define S_ 2048
#define D_ 512
#define H_ 8
#define HD_ 64
#define M_TOT 8192  // B_*S_

typedef __attribute__((ext_vector_type(8))) short short8;
typedef __attribute__((ext_vector_type(4))) float f32x4;
typedef unsigned short u16;
typedef unsigned int u32;

__device__ __forceinline__ u16 f2bf(float f) {
  union { float f; u32 u; } v; v.f = f;
  u32 u = v.u;
  return (u16)((u + 0x7fffu + ((u >> 16) & 1u)) >> 16);  // RNE
}

__device__ __forceinline__ void gload16(const void* g, void* l) {
  // width-16 global->LDS DMA; LDS dest = wave-uniform base + lane*16
  __builtin_amdgcn_global_load_lds(
      (const __attribute__((address_space(1))) unsigned int*)g,
      (__attribute__((address_space(3))) unsigned int*)l, 16, 0, 0);
}

// ---------------------------------------------------------------- cast to bf16
__global__ __launch_bounds__(256) void cast_kernel(
    const float* __restrict__ x, const float* __restrict__ wq, const float* __restrict__ wk,
    const float* __restrict__ wv, const float* __restrict__ wo,
    u16* __restrict__ xb, u16* __restrict__ wqb, u16* __restrict__ wkb,
    u16* __restrict__ wvb, u16* __restrict__ wob)
{
  const int NX = M_TOT * D_ / 4;  // 1048576 float4s
  const int NW = D_ * D_ / 4;     // 65536
  int i = blockIdx.x * 256 + threadIdx.x;
  const float* src; u16* dst; int o;
  if (i < NX)               { src = x;  dst = xb;  o = i; }
  else if (i < NX + NW)     { src = wq; dst = wqb; o = i - NX; }
  else if (i < NX + 2 * NW) { src = wk; dst = wkb; o = i - NX - NW; }
  else if (i < NX + 3 * NW) { src = wv; dst = wvb; o = i - NX - 2 * NW; }
  else if (i < NX + 4 * NW) { src = wo; dst = wob; o = i - NX - 3 * NW; }
  else return;
  f32x4 v = ((const f32x4*)src)[o];
  u32 p0 = (u32)f2bf(v[0]) | ((u32)f2bf(v[1]) << 16);
  u32 p1 = (u32)f2bf(v[2]) | ((u32)f2bf(v[3]) << 16);
  u32* d = (u32*)(dst + (long)o * 4);
  d[0] = p0; d[1] = p1;
}

// ---------------------------------------------------------------- bf16 GEMM, B^T weights
// C[m][n] = sum_k A[m][k]*Bw[n][k] (+bias)
// mode 0 (fused QKV, N=1536): n<512 -> Q (scaled 1/8) [bh][s][hd]
//                             n<1024 -> K [bh][s][hd]
//                             else   -> V TRANSPOSED [bh][hd][s]
// mode 1 (out-proj, N=512): out_f32[m*D+n] = C + bias[n] + resid[m*D+n]
#define BM 128
#define BN 128
#define BKK 64

__global__ __launch_bounds__(256) void gemm_bt(
    const u16* __restrict__ A, const u16* __restrict__ Bw,
    const float* __restrict__ b0, const float* __restrict__ b1, const float* __restrict__ b2,
    const float* __restrict__ resid,
    u16* __restrict__ oq, u16* __restrict__ ok, u16* __restrict__ ov,
    float* __restrict__ out_f32, int mode)
{
  __shared__ u16 As[BM * BKK];  // 16 KB, linear [row][128B] with XOR-swizzled contents
  __shared__ u16 Bs[BN * BKK];
  const int K = D_;
  const int tid = threadIdx.x;
  const int lane = tid & 63;
  const int wave = tid >> 6;
  const int wr = wave >> 1, wc = wave & 1;  // 2x2 waves, 64x64 each
  const int m0 = blockIdx.x * BM, n0 = blockIdx.y * BN;
  const int l15 = lane & 15, l4 = lane >> 4;

  f32x4 acc[4][4];
#pragma unroll
  for (int i = 0; i < 4; ++i)
#pragma unroll
    for (int j = 0; j < 4; ++j)
      acc[i][j] = (f32x4){0.f, 0.f, 0.f, 0.f};

  // staging geometry: per wave-inst, lane covers row (lane>>3), 16B chunk (lane&7)
  // LDS is LINEAR; the global SOURCE is inverse-swizzled (rule 21: both-sides-or-neither)
  const int srow_in_grp = lane >> 3;            // 0..7
  const int schunk = (lane & 7) * 16;           // byte chunk within 128B row
  const int ssw = (srow_in_grp & 7) << 4;       // row-XOR
  const char* Ab = (const char*)(A + (long)m0 * K);
  const char* Bb = (const char*)(Bw + (long)n0 * K);

  for (int k0 = 0; k0 < K; k0 += BKK) {
    __syncthreads();  // prior tile's frag reads done
#pragma unroll
    for (int i = 0; i < 4; ++i) {
      int rowbase = (wave * 4 + i) * 8;
      int row = rowbase + srow_in_grp;
      long gsrc = (long)row * (K * 2) + k0 * 2 + (schunk ^ ssw);
      gload16(Ab + gsrc, (char*)As + (wave * 4 + i) * 1024);
      gload16(Bb + gsrc, (char*)Bs + (wave * 4 + i) * 1024);
    }
    __syncthreads();  // drains vmcnt(0): tiles resident

#pragma unroll
    for (int kb = 0; kb < 2; ++kb) {
      short8 af[4], bf[4];
      const int cb = kb * 64 + l4 * 16;  // byte col within row
#pragma unroll
      for (int i = 0; i < 4; ++i) {
        int ra = wr * 64 + i * 16 + l15;
        int rb = wc * 64 + i * 16 + l15;
        af[i] = *(const short8*)((const char*)As + ra * 128 + (cb ^ ((ra & 7) << 4)));
        bf[i] = *(const short8*)((const char*)Bs + rb * 128 + (cb ^ ((rb & 7) << 4)));
      }
#pragma unroll
      for (int i = 0; i < 4; ++i)
#pragma unroll
        for (int j = 0; j < 4; ++j)
          acc[i][j] = __builtin_amdgcn_mfma_f32_16x16x32_bf16(af[i], bf[j], acc[i][j], 0, 0, 0);
    }
  }

  if (mode == 0) {
    const int which = n0 >> 9;  // block-uniform: 0=Q,1=K,2=V
    const float* bias = which == 0 ? b0 : (which == 1 ? b1 : b2);
    const float scale = which == 0 ? 0.125f : 1.0f;
    u16* outp = which == 0 ? oq : (which == 1 ? ok : ov);
#pragma unroll
    for (int i = 0; i < 4; ++i) {
#pragma unroll
      for (int j = 0; j < 4; ++j) {
        int n = n0 + wc * 64 + j * 16 + l15;
        int nn = n & 511;
        float bv = bias[nn];
        int h = nn >> 6, hd = nn & 63;
        int mbase = m0 + wr * 64 + i * 16 + l4 * 4;
        int b = mbase >> 11, s0 = mbase & 2047;
        if (which == 2) {
          // V^T: [bh][hd][s]; 4 consecutive s -> one 8B store
          union { u16 u[4]; unsigned long long ll; } pk;
#pragma unroll
          for (int r = 0; r < 4; ++r)
            pk.u[r] = f2bf(acc[i][j][r] + bv);
          *(unsigned long long*)&outp[((long)(b * H_ + h) * HD_ + hd) * S_ + s0] = pk.ll;
        } else {
#pragma unroll
          for (int r = 0; r < 4; ++r) {
            float v = (acc[i][j][r] + bv) * scale;
            outp[((long)(b * H_ + h) * S_ + s0 + r) * HD_ + hd] = f2bf(v);
          }
        }
      }
    }
  } else {
#pragma unroll
    for (int i = 0; i < 4; ++i) {
#pragma unroll
      for (int j = 0; j < 4; ++j) {
        int n = n0 + wc * 64 + j * 16 + l15;
        float bv = b0[n];
#pragma unroll
        for (int r = 0; r < 4; ++r) {
          int m = m0 + wr * 64 + i * 16 + l4 * 4 + r;
          long idx = (long)m * D_ + n;
          out_f32[idx] = acc[i][j][r] + bv + resid[idx];
        }
      }
    }
  }
}

// ---------------------------------------------------------------- flash attention
// Q pre-scaled by 1/8. K [bh][s][hd], Vt [bh][hd][s]: MFMA B-frags read DIRECTLY
// from global (L2-served; XCD swizzle keeps each head's 512KB on one XCD's L2).
// No K/V LDS staging, no __syncthreads. P goes through wave-private swizzled LDS.
__global__ __launch_bounds__(256) void attn_kernel(
    const u16* __restrict__ Qg, const u16* __restrict__ Kg,
    const u16* __restrict__ Vtg, u16* __restrict__ ctx)
{
  __shared__ u16 PsBuf[128 * 64];  // 16 KB; per-wave 32 rows x 128B, XOR-swizzled
  char* PsB = (char*)PsBuf;

  const int tid = threadIdx.x, lane = tid & 63, wave = tid >> 6;
  const int l15 = lane & 15, l4 = lane >> 4;
  const int lin = blockIdx.x;
  const int wg = (lin & 7) * 64 + (lin >> 3);  // XCD-chunked swizzle (512 = 8*64)
  const int bh = wg >> 4;
  const int q0 = (wg & 15) * 128;
  const int b = bh >> 3, h = bh & 7;
  const long hoff = (long)bh * S_ * HD_;
  const u16* Qh = Qg + hoff;
  const u16* Kh = Kg + hoff;
  const u16* Vth = Vtg + hoff;
  const int wrow = wave * 32;

  // Q fragments held in registers for the whole K/V sweep
  short8 qf[2][2];
#pragma unroll
  for (int mf = 0; mf < 2; ++mf)
#pragma unroll
    for (int kb = 0; kb < 2; ++kb) {
      int row = q0 + wrow + mf * 16 + l15;
      qf[mf][kb] = *(const short8*)&Qh[(long)row * HD_ + kb * 32 + l4 * 8];
    }

  float mst[2][4], lst[2][4];
  f32x4 oacc[2][4];
#pragma unroll
  for (int mf = 0; mf < 2; ++mf)
#pragma unroll
    for (int r = 0; r < 4; ++r) { mst[mf][r] = -1e30f; lst[mf][r] = 0.f; }
#pragma unroll
  for (int mf = 0; mf < 2; ++mf)
#pragma unroll
    for (int nf = 0; nf < 4; ++nf)
      oacc[mf][nf] = (f32x4){0.f, 0.f, 0.f, 0.f};

  for (int kv0 = 0; kv0 < S_; kv0 += 64) {
    // ---- S = Q @ K^T (K-frags direct from global)
    f32x4 sacc[2][4];
#pragma unroll
    for (int mf = 0; mf < 2; ++mf)
#pragma unroll
      for (int nf = 0; nf < 4; ++nf)
        sacc[mf][nf] = (f32x4){0.f, 0.f, 0.f, 0.f};
#pragma unroll
    for (int kb = 0; kb < 2; ++kb) {
      short8 kf[4];
#pragma unroll
      for (int nf = 0; nf < 4; ++nf)
        kf[nf] = *(const short8*)&Kh[(long)(kv0 + nf * 16 + l15) * HD_ + kb * 32 + l4 * 8];
#pragma unroll
      for (int mf = 0; mf < 2; ++mf)
#pragma unroll
        for (int nf = 0; nf < 4; ++nf)
          sacc[mf][nf] = __builtin_amdgcn_mfma_f32_16x16x32_bf16(qf[mf][kb], kf[nf], sacc[mf][nf], 0, 0, 0);
    }

    // ---- online softmax (reduce across the 16 col-lanes)
#pragma unroll
    for (int mf = 0; mf < 2; ++mf) {
#pragma unroll
      for (int r = 0; r < 4; ++r) {
        float mx = fmaxf(fmaxf(sacc[mf][0][r], sacc[mf][1][r]),
                         fmaxf(sacc[mf][2][r], sacc[mf][3][r]));
        mx = fmaxf(mx, __shfl_xor(mx, 1));
        mx = fmaxf(mx, __shfl_xor(mx, 2));
        mx = fmaxf(mx, __shfl_xor(mx, 4));
        mx = fmaxf(mx, __shfl_xor(mx, 8));
        float mnew = fmaxf(mst[mf][r], mx);
        float rs = __expf(mst[mf][r] - mnew);
        mst[mf][r] = mnew;
        float rsum = 0.f;
#pragma unroll
        for (int nf = 0; nf < 4; ++nf) {
          float p = __expf(sacc[mf][nf][r] - mnew);
          sacc[mf][nf][r] = p;
          rsum += p;
        }
        rsum += __shfl_xor(rsum, 1);
        rsum += __shfl_xor(rsum, 2);
        rsum += __shfl_xor(rsum, 4);
        rsum += __shfl_xor(rsum, 8);
        lst[mf][r] = lst[mf][r] * rs + rsum;
#pragma unroll
        for (int nf = 0; nf < 4; ++nf)
          oacc[mf][nf][r] *= rs;
      }
    }

    // ---- P -> bf16 -> wave-private LDS (swizzled rows)
#pragma unroll
    for (int mf = 0; mf < 2; ++mf)
#pragma unroll
      for (int nf = 0; nf < 4; ++nf)
#pragma unroll
        for (int r = 0; r < 4; ++r) {
          int prow = wrow + mf * 16 + l4 * 4 + r;
          int pcol = nf * 16 + l15;
          *(u16*)(PsB + prow * 128 + ((pcol * 2) ^ ((prow & 7) << 4))) = f2bf(sacc[mf][nf][r]);
        }
    asm volatile("s_waitcnt lgkmcnt(0)" ::: "memory");

    // ---- O += P @ V  (V^T-frags direct from global)
#pragma unroll
    for (int kvb = 0; kvb < 2; ++kvb) {
      short8 pf[2], vf[4];
#pragma unroll
      for (int mf = 0; mf < 2; ++mf) {
        int prow = wrow + mf * 16 + l15;
        pf[mf] = *(const short8*)(PsB + prow * 128 + ((kvb * 64 + l4 * 16) ^ ((prow & 7) << 4)));
      }
#pragma unroll
      for (int nf = 0; nf < 4; ++nf)
        vf[nf] = *(const short8*)&Vth[(long)(nf * 16 + l15) * S_ + kv0 + kvb * 32 + l4 * 8];
#pragma unroll
      for (int mf = 0; mf < 2; ++mf)
#pragma unroll
        for (int nf = 0; nf < 4; ++nf)
          oacc[mf][nf] = __builtin_amdgcn_mfma_f32_16x16x32_bf16(pf[mf], vf[nf], oacc[mf][nf], 0, 0, 0);
    }
  }

  // epilogue: normalize and write context [B,S,D]
#pragma unroll
  for (int mf = 0; mf < 2; ++mf) {
#pragma unroll
    for (int r = 0; r < 4; ++r) {
      float inv = 1.f / lst[mf][r];
      int s = q0 + wrow + mf * 16 + l4 * 4 + r;
#pragma unroll
      for (int nf = 0; nf < 4; ++nf) {
        int d = nf * 16 + l15;
        ctx[((long)(b * S_ + s)) * D_ + h * HD_ + d] = f2bf(oacc[mf][nf][r] * inv);
      }
    }
  }
}

// ---------------------------------------------------------------- LayerNorm (wave per row)
__global__ __launch_bounds__(256) void ln_kernel(
    const float* __restrict__ y, const float* __restrict__ gamma,
    const float* __restrict__ beta, float* __restrict__ out)
{
  const int lane = threadIdx.x & 63, wave = threadIdx.x >> 6;
  const long row = (long)blockIdx.x * 4 + wave;
  const float* yr = y + row * D_;
  f32x4 v0 = *(const f32x4*)&yr[lane * 8];
  f32x4 v1 = *(const f32x4*)&yr[lane * 8 + 4];
  float s = 0.f, ss = 0.f;
#pragma unroll
  for (int e = 0; e < 4; ++e) {
    s += v0[e]; ss += v0[e] * v0[e];
    s += v1[e]; ss += v1[e] * v1[e];
  }
#pragma unroll
  for (int msk = 1; msk < 64; msk <<= 1) {
    s += __shfl_xor(s, msk);
    ss += __shfl_xor(ss, msk);
  }
  float mean = s * (1.f / 512.f);
  float var = ss * (1.f / 512.f) - mean * mean;
  float inv = rsqrtf(var + 1e-5f);
  f32x4 g0 = *(const f32x4*)&gamma[lane * 8];
  f32x4 g1 = *(const f32x4*)&gamma[lane * 8 + 4];
  f32x4 b0 = *(const f32x4*)&beta[lane * 8];
  f32x4 b1 = *(const f32x4*)&beta[lane * 8 + 4];
  f32x4 o0, o1;
#pragma unroll
  for (int e = 0; e < 4; ++e) {
    o0[e] = (v0[e] - mean) * inv * g0[e] + b0[e];
    o1[e] = (v1[e] - mean) * inv * g1[e] + b1[e];
  }
  *(f32x4*)&out[row * D_ + lane * 8] = o0;
  *(f32x4*)&out[row * D_ + lane * 8 + 4] = o1;
}

// ---------------------------------------------------------------- launch
extern "C" void kernel_launch(void* const* d_in, const int* in_sizes, int n_in,
                              void* d_out, int out_size, void* d_ws, size_t ws_size,
                              hipStream_t stream) {
  const float* x  = (const float*)d_in[0];
  const float* Wq = (const float*)d_in[1];
  const float* bq = (const float*)d_in[2];
  const float* Wk = (const float*)d_in[3];
  const float* bk = (const float*)d_in[4];
  const float* Wv = (const float*)d_in[5];
  const float* bv = (const float*)d_in[6];
  const float* Wo = (const float*)d_in[7];
  const float* bo = (const float*)d_in[8];
  const float* lg = (const float*)d_in[9];
  const float* lb = (const float*)d_in[10];

  char* ws = (char*)d_ws;
  const size_t SZ_XB = (size_t)M_TOT * D_ * 2;  // 8 MiB per [M,D] bf16
  const size_t SZ_W  = (size_t)D_ * D_ * 2;
  u16* xb   = (u16*)(ws);
  u16* q_ws = (u16*)(ws + SZ_XB);
  u16* k_ws = (u16*)(ws + 2 * SZ_XB);
  u16* vt_ws= (u16*)(ws + 3 * SZ_XB);
  u16* c_ws = (u16*)(ws + 4 * SZ_XB);
  u16* wqb  = (u16*)(ws + 5 * SZ_XB);              // wq/wk/wv CONTIGUOUS: fused
  u16* wkb  = (u16*)(ws + 5 * SZ_XB + SZ_W);       //   GEMM indexes rows 0..1535
  u16* wvb  = (u16*)(ws + 5 * SZ_XB + 2 * SZ_W);
  u16* wob  = (u16*)(ws + 5 * SZ_XB + 3 * SZ_W);
  // y (fp32, 16 MiB) aliases xb+q_ws — both dead before out-proj writes it
  float* yf = (float*)(ws);

  cast_kernel<<<5120, 256, 0, stream>>>(x, Wq, Wk, Wv, Wo, xb, wqb, wkb, wvb, wob);

  // Fused QKV projection: N = 1536 (Q scaled 1/8; V written transposed)
  gemm_bt<<<dim3(M_TOT / BM, 1536 / BN), 256, 0, stream>>>(
      xb, wqb, bq, bk, bv, nullptr, q_ws, k_ws, vt_ws, nullptr, 0);

  attn_kernel<<<512, 256, 0, stream>>>(q_ws, k_ws, vt_ws, c_ws);

  // Out-proj + bias + residual (fp32 out)
  gemm_bt<<<dim3(M_TOT / BM, D_ / BN), 256, 0, stream>>>(
      c_ws, wob, bo, nullptr, nullptr, x, nullptr, nullptr, nullptr, yf, 1);

  ln_kernel<<<M_TOT / 4, 256, 0, stream>>>(yf, lg, lb, (float*)d_out);
}

// Round 7
// 243.287 us; speedup vs baseline: 1.3942x; 1.3207x over previous
//
#include <hip/hip_runtime.h>
#include <hip/hip_bf16.h>

#define B_ 4
#define S_ 2048
#define D_ 512
#define H_ 8
#define HD_ 64
#define M_TOT 8192  // B_*S_

typedef __attribute__((ext_vector_type(8))) short short8;
typedef __attribute__((ext_vector_type(4))) float f32x4;
typedef unsigned short u16;
typedef unsigned int u32;

__device__ __forceinline__ u16 f2bf(float f) {
  union { float f; u32 u; } v; v.f = f;
  u32 u = v.u;
  return (u16)((u + 0x7fffu + ((u >> 16) & 1u)) >> 16);  // RNE
}

__device__ __forceinline__ void gload16(const void* g, void* l) {
  // width-16 global->LDS DMA; LDS dest = wave-uniform base + lane*16
  __builtin_amdgcn_global_load_lds(
      (const __attribute__((address_space(1))) unsigned int*)g,
      (__attribute__((address_space(3))) unsigned int*)l, 16, 0, 0);
}

// ---------------------------------------------------------------- cast to bf16
__global__ __launch_bounds__(256) void cast_kernel(
    const float* __restrict__ x, const float* __restrict__ wq, const float* __restrict__ wk,
    const float* __restrict__ wv, const float* __restrict__ wo,
    u16* __restrict__ xb, u16* __restrict__ wqb, u16* __restrict__ wkb,
    u16* __restrict__ wvb, u16* __restrict__ wob)
{
  const int NX = M_TOT * D_ / 4;  // 1048576 float4s
  const int NW = D_ * D_ / 4;     // 65536
  int i = blockIdx.x * 256 + threadIdx.x;
  const float* src; u16* dst; int o;
  if (i < NX)               { src = x;  dst = xb;  o = i; }
  else if (i < NX + NW)     { src = wq; dst = wqb; o = i - NX; }
  else if (i < NX + 2 * NW) { src = wk; dst = wkb; o = i - NX - NW; }
  else if (i < NX + 3 * NW) { src = wv; dst = wvb; o = i - NX - 2 * NW; }
  else if (i < NX + 4 * NW) { src = wo; dst = wob; o = i - NX - 3 * NW; }
  else return;
  f32x4 v = ((const f32x4*)src)[o];
  u32 p0 = (u32)f2bf(v[0]) | ((u32)f2bf(v[1]) << 16);
  u32 p1 = (u32)f2bf(v[2]) | ((u32)f2bf(v[3]) << 16);
  u32* d = (u32*)(dst + (long)o * 4);
  d[0] = p0; d[1] = p1;
}

// ---------------------------------------------------------------- bf16 GEMM, B^T weights
// C[m][n] = sum_k A[m][k]*Bw[n][k] (+bias)
// mode 0 (fused QKV, N=1536): n<512 -> Q (scaled 1/8) [bh][s][hd]
//                             n<1024 -> K [bh][s][hd]
//                             else   -> V TRANSPOSED [bh][hd][s]
// mode 1 (out-proj, N=512): out_f32[m*D+n] = C + bias[n] + resid[m*D+n]
#define BM 128
#define BN 128
#define BKK 64

__global__ __launch_bounds__(256) void gemm_bt(
    const u16* __restrict__ A, const u16* __restrict__ Bw,
    const float* __restrict__ b0, const float* __restrict__ b1, const float* __restrict__ b2,
    const float* __restrict__ resid,
    u16* __restrict__ oq, u16* __restrict__ ok, u16* __restrict__ ov,
    float* __restrict__ out_f32, int mode)
{
  __shared__ u16 As[BM * BKK];  // 16 KB, linear [row][128B] with XOR-swizzled contents
  __shared__ u16 Bs[BN * BKK];
  const int K = D_;
  const int tid = threadIdx.x;
  const int lane = tid & 63;
  const int wave = tid >> 6;
  const int wr = wave >> 1, wc = wave & 1;  // 2x2 waves, 64x64 each
  const int m0 = blockIdx.x * BM, n0 = blockIdx.y * BN;
  const int l15 = lane & 15, l4 = lane >> 4;

  f32x4 acc[4][4];
#pragma unroll
  for (int i = 0; i < 4; ++i)
#pragma unroll
    for (int j = 0; j < 4; ++j)
      acc[i][j] = (f32x4){0.f, 0.f, 0.f, 0.f};

  // staging geometry: per wave-inst, lane covers row (lane>>3), 16B chunk (lane&7)
  // LDS is LINEAR; the global SOURCE is inverse-swizzled (rule 21)
  const int srow_in_grp = lane >> 3;            // 0..7
  const int schunk = (lane & 7) * 16;           // byte chunk within 128B row
  const int ssw = srow_in_grp << 4;             // row-XOR
  const char* Ab = (const char*)(A + (long)m0 * K);
  const char* Bb = (const char*)(Bw + (long)n0 * K);

  for (int k0 = 0; k0 < K; k0 += BKK) {
    __syncthreads();  // prior tile's frag reads done
#pragma unroll
    for (int i = 0; i < 4; ++i) {
      int row = (wave * 4 + i) * 8 + srow_in_grp;
      long gsrc = (long)row * (K * 2) + k0 * 2 + (schunk ^ ssw);
      gload16(Ab + gsrc, (char*)As + (wave * 4 + i) * 1024);
      gload16(Bb + gsrc, (char*)Bs + (wave * 4 + i) * 1024);
    }
    __syncthreads();  // drains vmcnt(0): tiles resident

#pragma unroll
    for (int kb = 0; kb < 2; ++kb) {
      short8 af[4], bf[4];
      const int cb = kb * 64 + l4 * 16;  // byte col within row
#pragma unroll
      for (int i = 0; i < 4; ++i) {
        int ra = wr * 64 + i * 16 + l15;
        int rb = wc * 64 + i * 16 + l15;
        af[i] = *(const short8*)((const char*)As + ra * 128 + (cb ^ ((ra & 7) << 4)));
        bf[i] = *(const short8*)((const char*)Bs + rb * 128 + (cb ^ ((rb & 7) << 4)));
      }
#pragma unroll
      for (int i = 0; i < 4; ++i)
#pragma unroll
        for (int j = 0; j < 4; ++j)
          acc[i][j] = __builtin_amdgcn_mfma_f32_16x16x32_bf16(af[i], bf[j], acc[i][j], 0, 0, 0);
    }
  }

  if (mode == 0) {
    const int which = n0 >> 9;  // block-uniform: 0=Q,1=K,2=V
    const float* bias = which == 0 ? b0 : (which == 1 ? b1 : b2);
    const float scale = which == 0 ? 0.125f : 1.0f;
    u16* outp = which == 0 ? oq : (which == 1 ? ok : ov);
#pragma unroll
    for (int i = 0; i < 4; ++i) {
#pragma unroll
      for (int j = 0; j < 4; ++j) {
        int n = n0 + wc * 64 + j * 16 + l15;
        int nn = n & 511;
        float bv = bias[nn];
        int h = nn >> 6, hd = nn & 63;
        int mbase = m0 + wr * 64 + i * 16 + l4 * 4;
        int b = mbase >> 11, s0 = mbase & 2047;
        if (which == 2) {
          // V^T: [bh][hd][s]; 4 consecutive s -> one 8B store
          union { u16 u[4]; unsigned long long ll; } pk;
#pragma unroll
          for (int r = 0; r < 4; ++r)
            pk.u[r] = f2bf(acc[i][j][r] + bv);
          *(unsigned long long*)&outp[((long)(b * H_ + h) * HD_ + hd) * S_ + s0] = pk.ll;
        } else {
#pragma unroll
          for (int r = 0; r < 4; ++r) {
            float v = (acc[i][j][r] + bv) * scale;
            outp[((long)(b * H_ + h) * S_ + s0 + r) * HD_ + hd] = f2bf(v);
          }
        }
      }
    }
  } else {
#pragma unroll
    for (int i = 0; i < 4; ++i) {
#pragma unroll
      for (int j = 0; j < 4; ++j) {
        int n = n0 + wc * 64 + j * 16 + l15;
        float bv = b0[n];
#pragma unroll
        for (int r = 0; r < 4; ++r) {
          int m = m0 + wr * 64 + i * 16 + l4 * 4 + r;
          long idx = (long)m * D_ + n;
          out_f32[idx] = acc[i][j][r] + bv + resid[idx];
        }
      }
    }
  }
}

// ---------------------------------------------------------------- flash attention
// Q pre-scaled by 1/8. K [bh][s][hd], Vt [bh][hd][s].
// TQ=64 (4 waves x 16 q-rows), TK=64. K and V^T tiles double-buffered in LDS via
// global_load_lds (linear dest, inverse-swizzled source, swizzled ds_read — rule 21).
// One __syncthreads per tile: stage(t+1) issued before compute(t), drained at the sync.
__global__ __launch_bounds__(256) void attn_kernel(
    const u16* __restrict__ Qg, const u16* __restrict__ Kg,
    const u16* __restrict__ Vtg, u16* __restrict__ ctx)
{
  __shared__ char Ks[2][8192];  // [kv 64][d 128B], XOR-swizzled contents
  __shared__ char Vs[2][8192];  // [d 64][kv 128B], XOR-swizzled contents
  __shared__ char Ps[8192];     // [q 64][kv 128B], wave-private rows, swizzled

  const int tid = threadIdx.x, lane = tid & 63, wave = tid >> 6;
  const int l15 = lane & 15, l4 = lane >> 4;
  const int lin = blockIdx.x;
  const int wg = (lin & 7) * 128 + (lin >> 3);  // XCD-chunked swizzle (1024 = 8*128)
  const int bh = wg >> 5;                       // 32 q-tiles per (b,h)
  const int q0 = (wg & 31) * 64;
  const int b = bh >> 3, h = bh & 7;
  const long hoff = (long)bh * S_ * HD_;
  const u16* Qh = Qg + hoff;
  const char* Kb = (const char*)(Kg + hoff);
  const char* Vb = (const char*)(Vtg + hoff);
  const int wrow = wave * 16;

  // staging geometry (per lane): row-in-inst = lane>>3, 16B chunk = lane&7
  const int srow = lane >> 3;
  const int soff = ((lane & 7) * 16) ^ (srow << 4);  // pre-swizzled byte in 128B window

  // Q fragments held in registers for the whole K/V sweep
  short8 qf[2];
#pragma unroll
  for (int kb = 0; kb < 2; ++kb)
    qf[kb] = *(const short8*)&Qh[(long)(q0 + wrow + l15) * HD_ + kb * 32 + l4 * 8];

  float mst[4], lst[4];
  f32x4 oacc[4];
#pragma unroll
  for (int r = 0; r < 4; ++r) { mst[r] = -1e30f; lst[r] = 0.f; }
#pragma unroll
  for (int nf = 0; nf < 4; ++nf)
    oacc[nf] = (f32x4){0.f, 0.f, 0.f, 0.f};

  // ---- prologue: stage tile 0
#pragma unroll
  for (int j = 0; j < 2; ++j) {
    int r = wrow + j * 8 + srow;
    gload16(Kb + (long)r * 128 + soff, Ks[0] + (wave * 2 + j) * 1024);
    gload16(Vb + (long)r * 4096 + soff, Vs[0] + (wave * 2 + j) * 1024);
  }
  __syncthreads();

  for (int t = 0; t < S_ / 64; ++t) {
    const int cur = t & 1;
    // ---- issue next tile's staging (in flight during compute)
    if (t < S_ / 64 - 1) {
      const int kv1 = (t + 1) * 64;
#pragma unroll
      for (int j = 0; j < 2; ++j) {
        int r = wrow + j * 8 + srow;
        gload16(Kb + (long)(kv1 + r) * 128 + soff, Ks[cur ^ 1] + (wave * 2 + j) * 1024);
        gload16(Vb + (long)r * 4096 + (long)kv1 * 2 + soff, Vs[cur ^ 1] + (wave * 2 + j) * 1024);
      }
    }

    // ---- S = Q @ K^T
    f32x4 sacc[4];
#pragma unroll
    for (int nf = 0; nf < 4; ++nf)
      sacc[nf] = (f32x4){0.f, 0.f, 0.f, 0.f};
#pragma unroll
    for (int kb = 0; kb < 2; ++kb) {
      const int cb = kb * 64 + l4 * 16;
      short8 kf[4];
#pragma unroll
      for (int nf = 0; nf < 4; ++nf) {
        int row = nf * 16 + l15;
        kf[nf] = *(const short8*)(Ks[cur] + row * 128 + (cb ^ ((row & 7) << 4)));
      }
#pragma unroll
      for (int nf = 0; nf < 4; ++nf)
        sacc[nf] = __builtin_amdgcn_mfma_f32_16x16x32_bf16(qf[kb], kf[nf], sacc[nf], 0, 0, 0);
    }

    // ---- online softmax (reduce across the 16 col-lanes)
#pragma unroll
    for (int r = 0; r < 4; ++r) {
      float mx = fmaxf(fmaxf(sacc[0][r], sacc[1][r]), fmaxf(sacc[2][r], sacc[3][r]));
      mx = fmaxf(mx, __shfl_xor(mx, 1));
      mx = fmaxf(mx, __shfl_xor(mx, 2));
      mx = fmaxf(mx, __shfl_xor(mx, 4));
      mx = fmaxf(mx, __shfl_xor(mx, 8));
      float mnew = fmaxf(mst[r], mx);
      float rs = __expf(mst[r] - mnew);
      mst[r] = mnew;
      float rsum = 0.f;
#pragma unroll
      for (int nf = 0; nf < 4; ++nf) {
        float p = __expf(sacc[nf][r] - mnew);
        sacc[nf][r] = p;
        rsum += p;
      }
      rsum += __shfl_xor(rsum, 1);
      rsum += __shfl_xor(rsum, 2);
      rsum += __shfl_xor(rsum, 4);
      rsum += __shfl_xor(rsum, 8);
      lst[r] = lst[r] * rs + rsum;
#pragma unroll
      for (int nf = 0; nf < 4; ++nf)
        oacc[nf][r] *= rs;
    }

    // ---- P -> bf16 -> wave-private LDS rows (swizzled)
#pragma unroll
    for (int nf = 0; nf < 4; ++nf)
#pragma unroll
      for (int r = 0; r < 4; ++r) {
        int prow = wrow + l4 * 4 + r;
        int pcol = nf * 16 + l15;
        *(u16*)(Ps + prow * 128 + ((pcol * 2) ^ ((prow & 7) << 4))) = f2bf(sacc[nf][r]);
      }
    asm volatile("s_waitcnt lgkmcnt(0)" ::: "memory");

    // ---- O += P @ V
#pragma unroll
    for (int kvb = 0; kvb < 2; ++kvb) {
      const int cb = kvb * 64 + l4 * 16;
      short8 pf, vf[4];
      {
        int prow = wrow + l15;
        pf = *(const short8*)(Ps + prow * 128 + (cb ^ ((prow & 7) << 4)));
      }
#pragma unroll
      for (int nf = 0; nf < 4; ++nf) {
        int row = nf * 16 + l15;
        vf[nf] = *(const short8*)(Vs[cur] + row * 128 + (cb ^ ((row & 7) << 4)));
      }
#pragma unroll
      for (int nf = 0; nf < 4; ++nf)
        oacc[nf] = __builtin_amdgcn_mfma_f32_16x16x32_bf16(pf, vf[nf], oacc[nf], 0, 0, 0);
    }

    __syncthreads();  // drains vmcnt (next tile staged) + all waves done with cur
  }

  // epilogue: normalize and write context [B,S,D]
#pragma unroll
  for (int r = 0; r < 4; ++r) {
    float inv = 1.f / lst[r];
    int s = q0 + wrow + l4 * 4 + r;
#pragma unroll
    for (int nf = 0; nf < 4; ++nf) {
      int d = nf * 16 + l15;
      ctx[((long)(b * S_ + s)) * D_ + h * HD_ + d] = f2bf(oacc[nf][r] * inv);
    }
  }
}

// ---------------------------------------------------------------- LayerNorm (wave per row)
__global__ __launch_bounds__(256) void ln_kernel(
    const float* __restrict__ y, const float* __restrict__ gamma,
    const float* __restrict__ beta, float* __restrict__ out)
{
  const int lane = threadIdx.x & 63, wave = threadIdx.x >> 6;
  const long row = (long)blockIdx.x * 4 + wave;
  const float* yr = y + row * D_;
  f32x4 v0 = *(const f32x4*)&yr[lane * 8];
  f32x4 v1 = *(const f32x4*)&yr[lane * 8 + 4];
  float s = 0.f, ss = 0.f;
#pragma unroll
  for (int e = 0; e < 4; ++e) {
    s += v0[e]; ss += v0[e] * v0[e];
    s += v1[e]; ss += v1[e] * v1[e];
  }
#pragma unroll
  for (int msk = 1; msk < 64; msk <<= 1) {
    s += __shfl_xor(s, msk);
    ss += __shfl_xor(ss, msk);
  }
  float mean = s * (1.f / 512.f);
  float var = ss * (1.f / 512.f) - mean * mean;
  float inv = rsqrtf(var + 1e-5f);
  f32x4 g0 = *(const f32x4*)&gamma[lane * 8];
  f32x4 g1 = *(const f32x4*)&gamma[lane * 8 + 4];
  f32x4 b0 = *(const f32x4*)&beta[lane * 8];
  f32x4 b1 = *(const f32x4*)&beta[lane * 8 + 4];
  f32x4 o0, o1;
#pragma unroll
  for (int e = 0; e < 4; ++e) {
    o0[e] = (v0[e] - mean) * inv * g0[e] + b0[e];
    o1[e] = (v1[e] - mean) * inv * g1[e] + b1[e];
  }
  *(f32x4*)&out[row * D_ + lane * 8] = o0;
  *(f32x4*)&out[row * D_ + lane * 8 + 4] = o1;
}

// ---------------------------------------------------------------- launch
extern "C" void kernel_launch(void* const* d_in, const int* in_sizes, int n_in,
                              void* d_out, int out_size, void* d_ws, size_t ws_size,
                              hipStream_t stream) {
  const float* x  = (const float*)d_in[0];
  const float* Wq = (const float*)d_in[1];
  const float* bq = (const float*)d_in[2];
  const float* Wk = (const float*)d_in[3];
  const float* bk = (const float*)d_in[4];
  const float* Wv = (const float*)d_in[5];
  const float* bv = (const float*)d_in[6];
  const float* Wo = (const float*)d_in[7];
  const float* bo = (const float*)d_in[8];
  const float* lg = (const float*)d_in[9];
  const float* lb = (const float*)d_in[10];

  char* ws = (char*)d_ws;
  const size_t SZ_XB = (size_t)M_TOT * D_ * 2;  // 8 MiB per [M,D] bf16
  const size_t SZ_W  = (size_t)D_ * D_ * 2;
  u16* xb   = (u16*)(ws);
  u16* q_ws = (u16*)(ws + SZ_XB);
  u16* k_ws = (u16*)(ws + 2 * SZ_XB);
  u16* vt_ws= (u16*)(ws + 3 * SZ_XB);
  u16* c_ws = (u16*)(ws + 4 * SZ_XB);
  u16* wqb  = (u16*)(ws + 5 * SZ_XB);              // wq/wk/wv CONTIGUOUS: fused
  u16* wkb  = (u16*)(ws + 5 * SZ_XB + SZ_W);       //   GEMM indexes rows 0..1535
  u16* wvb  = (u16*)(ws + 5 * SZ_XB + 2 * SZ_W);
  u16* wob  = (u16*)(ws + 5 * SZ_XB + 3 * SZ_W);
  // y (fp32, 16 MiB) aliases xb+q_ws — both dead before out-proj writes it
  float* yf = (float*)(ws);

  cast_kernel<<<5120, 256, 0, stream>>>(x, Wq, Wk, Wv, Wo, xb, wqb, wkb, wvb, wob);

  // Fused QKV projection: N = 1536 (Q scaled 1/8; V written transposed)
  gemm_bt<<<dim3(M_TOT / BM, 1536 / BN), 256, 0, stream>>>(
      xb, wqb, bq, bk, bv, nullptr, q_ws, k_ws, vt_ws, nullptr, 0);

  attn_kernel<<<1024, 256, 0, stream>>>(q_ws, k_ws, vt_ws, c_ws);

  // Out-proj + bias + residual (fp32 out)
  gemm_bt<<<dim3(M_TOT / BM, D_ / BN), 256, 0, stream>>>(
      c_ws, wob, bo, nullptr, nullptr, x, nullptr, nullptr, nullptr, yf, 1);

  ln_kernel<<<M_TOT / 4, 256, 0, stream>>>(yf, lg, lb, (float*)d_out);
}